// Round 3
// baseline (3997.182 us; speedup 1.0000x reference)
//
#include <hip/hip_runtime.h>
#include <hip/hip_bf16.h>
#include <math.h>

// Problem constants
constexpr int CB_ = 32;    // batch
constexpr int CT = 256;    // T (= d_model of blocks' last dim)
constexpr int CF = 512;    // F (= sequence/channel dim inside blocks)
constexpr int CN = 508;    // N = F - M
constexpr int CM = 4;      // time-mark feats
constexpr int CT2 = 512;   // 2T
constexpr int MROWS = CB_ * CF;  // 16384 rows for row-major GEMMs

__device__ __forceinline__ float silu_f(float x) { return x / (1.0f + expf(-x)); }
__device__ __forceinline__ float softplus_f(float x) {
    return fmaxf(x, 0.0f) + log1pf(expf(-fabsf(x)));
}

// ---------------- stats: per (b,n) mean/stdev over T ----------------
__global__ void stats_kernel(const float* __restrict__ xe, float* __restrict__ means,
                             float* __restrict__ stdev) {
    int idx = blockIdx.x * blockDim.x + threadIdx.x;  // b*CN + n
    if (idx >= CB_ * CN) return;
    int b = idx / CN, n = idx - b * CN;
    const float* p = xe + (size_t)b * CT * CN + n;
    float s = 0.f;
    for (int t = 0; t < CT; t++) s += p[t * CN];
    float mean = s * (1.0f / CT);
    float v = 0.f;
    for (int t = 0; t < CT; t++) {
        float d = p[t * CN] - mean;
        v += d * d;
    }
    v *= (1.0f / CT);
    means[idx] = mean;
    stdev[idx] = sqrtf(v + 1e-5f);
}

// ---------------- build X: (B, F, T) fp32, f<508 normalized x_enc^T, f>=508 marks ---
__global__ void build_x_kernel(const float* __restrict__ xe, const float* __restrict__ xm,
                               const float* __restrict__ means, const float* __restrict__ stdev,
                               float* __restrict__ X) {
    int idx = blockIdx.x * blockDim.x + threadIdx.x;  // b*F*T + f*T + t
    if (idx >= CB_ * CF * CT) return;
    int t = idx & (CT - 1);
    int f = (idx >> 8) & (CF - 1);
    int b = idx >> 17;
    float val;
    if (f < CN) {
        int sn = b * CN + f;
        val = (xe[(size_t)b * CT * CN + t * CN + f] - means[sn]) / stdev[sn];
    } else {
        val = xm[(size_t)b * CT * CM + t * CM + (f - CN)];
    }
    X[idx] = val;
}

// ---------------- rmsnorm over last dim (256) ----------------
__global__ __launch_bounds__(256) void rmsnorm_kernel(const float* __restrict__ X,
                                                      const float* __restrict__ nw,
                                                      float* __restrict__ XN) {
    __shared__ float red[4];
    int row = blockIdx.x;  // b*F+f
    int t = threadIdx.x;
    float v = X[(size_t)row * CT + t];
    float ss = v * v;
    #pragma unroll
    for (int o = 32; o > 0; o >>= 1) ss += __shfl_down(ss, o);
    if ((t & 63) == 0) red[t >> 6] = ss;
    __syncthreads();
    float total = red[0] + red[1] + red[2] + red[3];
    float scale = rsqrtf(total * (1.0f / CT) + 1e-5f);
    XN[(size_t)row * CT + t] = v * scale * nw[t];
}

// ---------------- generic tiled GEMM: C = A(MROWS x K) @ W(K x Ncols) + bias ---------
// ACT: 0 = none, 1 = silu
template <int K, int ACT>
__global__ __launch_bounds__(256) void gemm_kernel(const float* __restrict__ A,
                                                   const float* __restrict__ W,
                                                   const float* __restrict__ bias,
                                                   float* __restrict__ C, int Ncols) {
    __shared__ float As[16][68];
    __shared__ float Bs[16][68];
    int tid = threadIdx.x;
    int m0 = blockIdx.x * 64, n0 = blockIdx.y * 64;
    int tx = tid & 15, ty = tid >> 4;
    float acc[4][4] = {};
    int am = tid >> 2;         // 0..63
    int ak = (tid & 3) * 4;    // 0,4,8,12
    int wk = tid >> 4;         // 0..15
    int wn = (tid & 15) * 4;   // 0..60
    for (int k0 = 0; k0 < K; k0 += 16) {
        float4 av = *(const float4*)(A + (size_t)(m0 + am) * K + k0 + ak);
        As[ak + 0][am] = av.x;
        As[ak + 1][am] = av.y;
        As[ak + 2][am] = av.z;
        As[ak + 3][am] = av.w;
        float4 wv = *(const float4*)(W + (size_t)(k0 + wk) * Ncols + n0 + wn);
        Bs[wk][wn + 0] = wv.x;
        Bs[wk][wn + 1] = wv.y;
        Bs[wk][wn + 2] = wv.z;
        Bs[wk][wn + 3] = wv.w;
        __syncthreads();
        #pragma unroll
        for (int kk = 0; kk < 16; kk++) {
            float4 a = *(const float4*)&As[kk][ty * 4];
            float4 bb = *(const float4*)&Bs[kk][tx * 4];
            acc[0][0] += a.x * bb.x; acc[0][1] += a.x * bb.y; acc[0][2] += a.x * bb.z; acc[0][3] += a.x * bb.w;
            acc[1][0] += a.y * bb.x; acc[1][1] += a.y * bb.y; acc[1][2] += a.y * bb.z; acc[1][3] += a.y * bb.w;
            acc[2][0] += a.z * bb.x; acc[2][1] += a.z * bb.y; acc[2][2] += a.z * bb.z; acc[2][3] += a.z * bb.w;
            acc[3][0] += a.w * bb.x; acc[3][1] += a.w * bb.y; acc[3][2] += a.w * bb.z; acc[3][3] += a.w * bb.w;
        }
        __syncthreads();
    }
    float bv[4];
    #pragma unroll
    for (int j = 0; j < 4; j++) bv[j] = bias[n0 + tx * 4 + j];
    #pragma unroll
    for (int i = 0; i < 4; i++) {
        float4 r;
        r.x = acc[i][0] + bv[0];
        r.y = acc[i][1] + bv[1];
        r.z = acc[i][2] + bv[2];
        r.w = acc[i][3] + bv[3];
        if (ACT == 1) {
            r.x = silu_f(r.x); r.y = silu_f(r.y); r.z = silu_f(r.z); r.w = silu_f(r.w);
        }
        *(float4*)(C + (size_t)(m0 + ty * 4 + i) * Ncols + n0 + tx * 4) = r;
    }
}

// ---------------- conv1d (channels=512, len=512, k=3, pad=1) + bias + silu ----------
__global__ __launch_bounds__(256) void conv_kernel(const float* __restrict__ Xp,
                                                   const float* __restrict__ W,
                                                   const float* __restrict__ bias,
                                                   float* __restrict__ Out) {
    __shared__ float Ws[64][50];  // [co][ci*3+k] for ci-chunk of 16 (48) +2 pad
    __shared__ float Xs[16][68];  // [ci][l0-1 .. l0+64]
    int tid = threadIdx.x;
    int co0 = blockIdx.x * 64, l0 = blockIdx.y * 64, b = blockIdx.z;
    const float* xb = Xp + (size_t)b * CF * CT2;
    int tx = tid & 15, ty = tid >> 4;
    float acc[4][4] = {};
    for (int c0 = 0; c0 < CF; c0 += 16) {
        {
            int co = tid >> 2;
            int j0 = (tid & 3) * 12;
            const float* wp = W + (size_t)(co0 + co) * (CF * 3) + c0 * 3 + j0;
            #pragma unroll
            for (int j = 0; j < 12; j++) Ws[co][j0 + j] = wp[j];
        }
        for (int e = tid; e < 16 * 66; e += 256) {
            int ci = e / 66, lo = e - ci * 66;
            int l = l0 - 1 + lo;
            Xs[ci][lo] = (l >= 0 && l < CT2) ? xb[(size_t)(c0 + ci) * CT2 + l] : 0.0f;
        }
        __syncthreads();
        #pragma unroll
        for (int kk = 0; kk < 16; kk++) {
            float xv[6];
            #pragma unroll
            for (int j = 0; j < 6; j++) xv[j] = Xs[kk][tx * 4 + j];
            #pragma unroll
            for (int i = 0; i < 4; i++) {
                float w0 = Ws[ty * 4 + i][kk * 3 + 0];
                float w1 = Ws[ty * 4 + i][kk * 3 + 1];
                float w2 = Ws[ty * 4 + i][kk * 3 + 2];
                #pragma unroll
                for (int j = 0; j < 4; j++)
                    acc[i][j] += w0 * xv[j] + w1 * xv[j + 1] + w2 * xv[j + 2];
            }
        }
        __syncthreads();
    }
    #pragma unroll
    for (int i = 0; i < 4; i++) {
        int co = co0 + ty * 4 + i;
        float bv = bias[co];
        #pragma unroll
        for (int j = 0; j < 4; j++) {
            float r = acc[i][j] + bv;
            Out[(size_t)b * CF * CT2 + (size_t)co * CT2 + l0 + tx * 4 + j] = silu_f(r);
        }
    }
}

// ---------------- cb[b,l] = dot(Bmat[b,l,:], Cmat[b,l,:]) over 256 ----------------
__global__ void cb_kernel(const float* __restrict__ Bm, const float* __restrict__ Cm,
                          float* __restrict__ cb) {
    int row = blockIdx.x;       // b*512 + l
    int lane = threadIdx.x;     // 64
    const float4* bp = (const float4*)(Bm + (size_t)row * CT);
    const float4* cp = (const float4*)(Cm + (size_t)row * CT);
    float4 bv = bp[lane];
    float4 cv = cp[lane];
    float s = bv.x * cv.x + bv.y * cv.y + bv.z * cv.z + bv.w * cv.w;
    #pragma unroll
    for (int o = 32; o > 0; o >>= 1) s += __shfl_down(s, o);
    if (lane == 0) cb[row] = s;
}

// ---------------- s6 gate: g = silu(softplus(P) * xco * cb[row]) * xres -------------
__global__ void s6_gate_kernel(float* __restrict__ P, const float* __restrict__ xco,
                               const float* __restrict__ cbv, const float* __restrict__ xres) {
    int idx = blockIdx.x * blockDim.x + threadIdx.x;  // B*512*512
    if (idx >= CB_ * CF * CT2) return;
    int row = idx >> 9;  // /512
    float delta = softplus_f(P[idx]);
    float xssm = delta * xco[idx] * cbv[row];
    P[idx] = silu_f(xssm) * xres[idx];
}

// ---------------- final: out[b,t,n] = DEC[b,n,t]*stdev + means ----------------
__global__ void out_kernel(const float* __restrict__ DEC, const float* __restrict__ means,
                           const float* __restrict__ stdev, float* __restrict__ out) {
    int idx = blockIdx.x * blockDim.x + threadIdx.x;  // b*T*N + t*N + n
    if (idx >= CB_ * CT * CN) return;
    int n = idx % CN;
    int bt = idx / CN;
    int t = bt & (CT - 1);
    int b = bt >> 8;
    int sn = b * CN + n;
    out[idx] = DEC[(size_t)b * CF * CT + (size_t)n * CT + t] * stdev[sn] + means[sn];
}

extern "C" void kernel_launch(void* const* d_in, const int* in_sizes, int n_in,
                              void* d_out, int out_size, void* d_ws, size_t ws_size,
                              hipStream_t stream) {
    // Reference dtypes are float32 for ALL tensors (setup_inputs uses jnp.float32).
    const float* x_enc  = (const float*)d_in[0];
    const float* x_mark = (const float*)d_in[1];
    const float* norm_w = (const float*)d_in[4];
    const float* inp_W  = (const float*)d_in[5];
    const float* inp_b  = (const float*)d_in[6];
    const float* conv_W = (const float*)d_in[7];
    const float* conv_b = (const float*)d_in[8];
    const float* convlin_W = (const float*)d_in[9];
    const float* convlin_b = (const float*)d_in[10];
    const float* fc1_W = (const float*)d_in[11];
    const float* fc1_b = (const float*)d_in[12];
    const float* fc2_W = (const float*)d_in[13];
    const float* fc2_b = (const float*)d_in[14];
    const float* fc3_W = (const float*)d_in[15];
    const float* fc3_b = (const float*)d_in[16];
    const float* D_W   = (const float*)d_in[17];
    const float* D_b   = (const float*)d_in[18];
    const float* out_W = (const float*)d_in[19];
    const float* out_b = (const float*)d_in[20];
    const float* proj_W = (const float*)d_in[21];
    const float* proj_b = (const float*)d_in[22];

    // Workspace: small buffers first, then three 33.55 MB rotating fp32 pools.
    // Total 96.2 MB.
    char* ws = (char*)d_ws;
    float* CBv   = (float*)(ws);             // 64 KB used
    float* MEANS = (float*)(ws + 65536);
    float* STDEV = (float*)(ws + 131072);
    const size_t POOL = 33554432;            // 16384 x 512 fp32 bytes
    const size_t HALF = 16777216 / 4;        // element offset: 16384 x 256 floats
    float* pool[3] = {
        (float*)(ws + 196608),
        (float*)(ws + 196608 + POOL),
        (float*)(ws + 196608 + 2 * POOL),
    };
    float* out = (float*)d_out;

    // stats + input construction: x in pool[0].lo  [B*F, 256]
    stats_kernel<<<(CB_ * CN + 255) / 256, 256, 0, stream>>>(x_enc, MEANS, STDEV);
    build_x_kernel<<<(CB_ * CF * CT) / 256, 256, 0, stream>>>(x_enc, x_mark, MEANS, STDEV, pool[0]);

    for (int i = 0; i < 3; i++) {
        const float* nw  = norm_w + i * CT;
        const float* iW  = inp_W + (size_t)i * CT * CT2;
        const float* ib  = inp_b + i * CT2;
        const float* cW  = conv_W + (size_t)i * CF * CF * 3;
        const float* cb_ = conv_b + i * CF;
        const float* clW = convlin_W + (size_t)i * CT2 * CT2;
        const float* clb = convlin_b + i * CT2;
        const float* f1W = fc1_W + (size_t)i * CT2 * CT2;
        const float* f1b = fc1_b + i * CT2;
        const float* f2W = fc2_W + (size_t)i * CT2 * CT;
        const float* f2b = fc2_b + i * CT;
        const float* f3W = fc3_W + (size_t)i * CT2 * CT;
        const float* f3b = fc3_b + i * CT;
        const float* dW  = D_W + (size_t)i * CT * CT2;
        const float* db  = D_b + i * CT2;
        const float* oW  = out_W + (size_t)i * CT2 * CT;
        const float* ob  = out_b + i * CT;

        float* A  = pool[i % 3];        // x in A.lo; xn -> A.hi; later Bmat/Cmat; then P/gate
        float* Bp = pool[(i + 1) % 3];  // xp -> xco; then x_next in Bp.lo
        float* Cp = pool[(i + 2) % 3];  // xc; then xres
        float* X  = A;
        float* XN = A + HALF;

        // xn = rmsnorm(x)
        rmsnorm_kernel<<<MROWS, 256, 0, stream>>>(X, nw, XN);
        // xp = xn @ inp_W + inp_b   -> Bp
        gemm_kernel<256, 0><<<dim3(MROWS / 64, CT2 / 64), 256, 0, stream>>>(XN, iW, ib, Bp, CT2);
        // xc = silu(conv(xp))       -> Cp
        conv_kernel<<<dim3(CF / 64, CT2 / 64, CB_), 256, 0, stream>>>(Bp, cW, cb_, Cp);
        // xco = xc @ convlin + b    -> Bp (xp dead)
        gemm_kernel<512, 0><<<dim3(MROWS / 64, CT2 / 64), 256, 0, stream>>>(Cp, clW, clb, Bp, CT2);
        // xres = silu(xn @ D_W + D_b) -> Cp (xc dead)
        gemm_kernel<256, 1><<<dim3(MROWS / 64, CT2 / 64), 256, 0, stream>>>(XN, dW, db, Cp, CT2);
        // Bmat = xco @ fc2 + b      -> A.lo (x dead)
        gemm_kernel<512, 0><<<dim3(MROWS / 64, CT / 64), 256, 0, stream>>>(Bp, f2W, f2b, X, CT);
        // Cmat = xco @ fc3 + b      -> A.hi (xn dead)
        gemm_kernel<512, 0><<<dim3(MROWS / 64, CT / 64), 256, 0, stream>>>(Bp, f3W, f3b, XN, CT);
        // cb = dot(Bmat, Cmat)
        cb_kernel<<<MROWS, 64, 0, stream>>>(X, XN, CBv);
        // P = xco @ fc1 + b         -> A full (Bmat/Cmat dead)
        gemm_kernel<512, 0><<<dim3(MROWS / 64, CT2 / 64), 256, 0, stream>>>(Bp, f1W, f1b, A, CT2);
        // g = silu(softplus(P)*xco*cb) * xres  (in-place on A)
        s6_gate_kernel<<<(CB_ * CF * CT2) / 256, 256, 0, stream>>>(A, Bp, CBv, Cp);
        // x_out = g @ out_W + out_b -> Bp.lo (xco dead)
        gemm_kernel<512, 0><<<dim3(MROWS / 64, CT / 64), 256, 0, stream>>>(A, oW, ob, Bp, CT);
    }

    // after 3 rotations x lives in pool[0].lo
    // dec = x @ proj_W + proj_b -> pool[1].lo  [B*F, 256]
    gemm_kernel<256, 0><<<dim3(MROWS / 64, CT / 64), 256, 0, stream>>>(pool[0], proj_W, proj_b, pool[1], CT);
    // out[b,t,n] = dec[b,n,t]*stdev + means
    out_kernel<<<(CB_ * CT * CN + 255) / 256, 256, 0, stream>>>(pool[1], MEANS, STDEV, out);
}

// Round 4
// 838.832 us; speedup vs baseline: 4.7652x; 4.7652x over previous
//
#include <hip/hip_runtime.h>
#include <hip/hip_bf16.h>
#include <math.h>

typedef __hip_bfloat16 bf16;
typedef short short8 __attribute__((ext_vector_type(8)));
typedef float floatx4 __attribute__((ext_vector_type(4)));

// Problem constants
constexpr int CB_ = 32;    // batch
constexpr int CT = 256;    // T
constexpr int CF = 512;    // F (channel/row dim inside blocks)
constexpr int CN = 508;    // N = F - M
constexpr int CM = 4;      // time-mark feats
constexpr int CT2 = 512;   // 2T
constexpr int MROWS = CB_ * CF;  // 16384
constexpr int PADL = 514;  // xpT padded length (l=-1..512)

__device__ __forceinline__ float b2f(bf16 v) { return __bfloat162float(v); }
__device__ __forceinline__ bf16 f2b(float v) { return __float2bfloat16(v); }
__device__ __forceinline__ float silu_f(float x) { return x / (1.0f + expf(-x)); }
__device__ __forceinline__ float softplus_f(float x) {
    return fmaxf(x, 0.0f) + log1pf(expf(-fabsf(x)));
}

// async global->LDS, 16B per lane (m97 pattern). lds base must be wave-uniform;
// HW deposits at ldsbase + lane*16.
__device__ __forceinline__ void gl_lds16(const bf16* g, short* l) {
    __builtin_amdgcn_global_load_lds(
        (const __attribute__((address_space(1))) unsigned int*)(g),
        (__attribute__((address_space(3))) unsigned int*)(l), 16, 0, 0);
}

// ---------------- weight prepack: W (K x N fp32) -> Wt (N x K bf16), z = matrix idx
__global__ __launch_bounds__(256) void wt_kernel(const float* __restrict__ src,
                                                 bf16* __restrict__ dst, int K, int N) {
    __shared__ float Ts[32][33];
    int n0 = blockIdx.x * 32, k0 = blockIdx.y * 32;
    const float* s = src + (size_t)blockIdx.z * K * N;
    bf16* d = dst + (size_t)blockIdx.z * K * N;
    for (int e = threadIdx.x; e < 1024; e += 256) {
        int r = e >> 5, c = e & 31;  // r: k, c: n
        Ts[r][c] = s[(size_t)(k0 + r) * N + n0 + c];
    }
    __syncthreads();
    for (int e = threadIdx.x; e < 1024; e += 256) {
        int r = e >> 5, c = e & 31;  // r: n, c: k
        d[(size_t)(n0 + r) * K + k0 + c] = f2b(Ts[c][r]);
    }
}

// ---------------- conv weight pack: src [3][co][ci][tap] fp32 -> dst [3][tap][co][ci] bf16
__global__ void convpack_kernel(const float* __restrict__ src, bf16* __restrict__ dst) {
    int idx = blockIdx.x * 256 + threadIdx.x;  // 3*3*512*512
    int ci = idx & 511;
    int co = (idx >> 9) & 511;
    int it = idx >> 18;        // i*3 + tap
    int tap = it % 3, ib = it / 3;
    dst[idx] = f2b(src[(((size_t)(ib * 512 + co)) * 512 + ci) * 3 + tap]);
}

// ---------------- stats: per (b,n) mean/stdev over T (fp32 input) ----------------
__global__ void stats_kernel(const float* __restrict__ xe, float* __restrict__ means,
                             float* __restrict__ stdev) {
    int idx = blockIdx.x * blockDim.x + threadIdx.x;
    if (idx >= CB_ * CN) return;
    int b = idx / CN, n = idx - b * CN;
    const float* p = xe + (size_t)b * CT * CN + n;
    float s = 0.f;
    for (int t = 0; t < CT; t++) s += p[t * CN];
    float mean = s * (1.0f / CT);
    float v = 0.f;
    for (int t = 0; t < CT; t++) {
        float d = p[t * CN] - mean;
        v += d * d;
    }
    v *= (1.0f / CT);
    means[idx] = mean;
    stdev[idx] = sqrtf(v + 1e-5f);
}

// ---------------- build X: (B, F, T) bf16 ----------------
__global__ void build_x_kernel(const float* __restrict__ xe, const float* __restrict__ xm,
                               const float* __restrict__ means, const float* __restrict__ stdev,
                               bf16* __restrict__ X) {
    int idx = blockIdx.x * blockDim.x + threadIdx.x;
    if (idx >= CB_ * CF * CT) return;
    int t = idx & (CT - 1);
    int f = (idx >> 8) & (CF - 1);
    int b = idx >> 17;
    float val;
    if (f < CN) {
        int sn = b * CN + f;
        val = (xe[(size_t)b * CT * CN + t * CN + f] - means[sn]) / stdev[sn];
    } else {
        val = xm[(size_t)b * CT * CM + t * CM + (f - CN)];
    }
    X[idx] = f2b(val);
}

// ---------------- rmsnorm over last dim (256), bf16 in/out ----------------
__global__ __launch_bounds__(256) void rmsnorm_kernel(const bf16* __restrict__ X,
                                                      const float* __restrict__ nw,
                                                      bf16* __restrict__ XN) {
    __shared__ float red[4];
    int row = blockIdx.x;
    int t = threadIdx.x;
    float v = b2f(X[(size_t)row * CT + t]);
    float ss = v * v;
    #pragma unroll
    for (int o = 32; o > 0; o >>= 1) ss += __shfl_down(ss, o);
    if ((t & 63) == 0) red[t >> 6] = ss;
    __syncthreads();
    float total = red[0] + red[1] + red[2] + red[3];
    float scale = rsqrtf(total * (1.0f / CT) + 1e-5f);
    XN[(size_t)row * CT + t] = f2b(v * scale * nw[t]);
}

// ---------------- MFMA GEMM: C(MxNcols) = A(MxK) @ Wt(NxK)^T + bias ----------------
// m97 structure: 128x128 tile, BK=32, global_load_lds 16B staging, 4 waves,
// each wave 4x4 tiles of 16x16x32 bf16 MFMA. ACT: 0 none, 1 silu.
template <int ACT>
__global__ __launch_bounds__(256) void mgemm_kernel(const bf16* __restrict__ A,
                                                    const bf16* __restrict__ Wt,
                                                    const float* __restrict__ bias,
                                                    bf16* __restrict__ C, int K, int Ncols) {
    __shared__ __align__(16) short As[128 * 32];
    __shared__ __align__(16) short Bs[128 * 32];
    const int tid = threadIdx.x;
    const int lane = tid & 63;
    const int wave = tid >> 6;
    const int m0 = blockIdx.x * 128, n0 = blockIdx.y * 128;

    const int srow0 = wave * 32;      // this wave stages rows srow0..srow0+31
    const int lrow = lane >> 2;       // row within 16-row instr
    const int lcol = (lane & 3) * 8;  // bf16 elem offset (16B granules)

    const bf16* aP0 = A + (size_t)(m0 + srow0 + lrow) * K + lcol;
    const bf16* aP1 = A + (size_t)(m0 + srow0 + 16 + lrow) * K + lcol;
    const bf16* bP0 = Wt + (size_t)(n0 + srow0 + lrow) * K + lcol;
    const bf16* bP1 = Wt + (size_t)(n0 + srow0 + 16 + lrow) * K + lcol;
    short* aL0 = &As[srow0 * 32];
    short* aL1 = &As[(srow0 + 16) * 32];
    short* bL0 = &Bs[srow0 * 32];
    short* bL1 = &Bs[(srow0 + 16) * 32];

    const int wm = (wave & 1) * 64, wn = (wave >> 1) * 64;
    const int fr = lane & 15, quad = lane >> 4;

    floatx4 acc[4][4];
    #pragma unroll
    for (int i = 0; i < 4; i++)
        #pragma unroll
        for (int j = 0; j < 4; j++) acc[i][j] = (floatx4){0.f, 0.f, 0.f, 0.f};

    for (int k0 = 0; k0 < K; k0 += 32) {
        gl_lds16(aP0 + k0, aL0);
        gl_lds16(aP1 + k0, aL1);
        gl_lds16(bP0 + k0, bL0);
        gl_lds16(bP1 + k0, bL1);
        __syncthreads();
        short8 af[4], bfv[4];
        #pragma unroll
        for (int i = 0; i < 4; i++) af[i] = *(const short8*)&As[(wm + i * 16 + fr) * 32 + quad * 8];
        #pragma unroll
        for (int j = 0; j < 4; j++) bfv[j] = *(const short8*)&Bs[(wn + j * 16 + fr) * 32 + quad * 8];
        #pragma unroll
        for (int i = 0; i < 4; i++)
            #pragma unroll
            for (int j = 0; j < 4; j++)
                acc[i][j] = __builtin_amdgcn_mfma_f32_16x16x32_bf16(af[i], bfv[j], acc[i][j], 0, 0, 0);
        __syncthreads();
    }
    // epilogue: C/D layout col=lane&15, row=quad*4+reg (m89-verified)
    #pragma unroll
    for (int j = 0; j < 4; j++) {
        int n = n0 + wn + j * 16 + fr;
        float bv = bias[n];
        #pragma unroll
        for (int i = 0; i < 4; i++) {
            int mb = m0 + wm + i * 16 + quad * 4;
            #pragma unroll
            for (int r = 0; r < 4; r++) {
                float v = acc[i][j][r] + bv;
                if (ACT == 1) v = silu_f(v);
                C[(size_t)(mb + r) * Ncols + n] = f2b(v);
            }
        }
    }
}

// ---------------- conv as implicit MFMA GEMM over (tap, ci), per batch ----------------
// Out[b,co,l] = silu( sum_tap sum_ci Wc[tap][co][ci] * xpT[b][l+tap][ci] + bias[co] )
// (xpT row l+tap encodes input l+tap-1 with pad rows 0 and 513 zeroed)
__global__ __launch_bounds__(256) void conv_mfma_kernel(const bf16* __restrict__ Wc,
                                                        const bf16* __restrict__ xpT,
                                                        const float* __restrict__ bias,
                                                        bf16* __restrict__ Out) {
    __shared__ __align__(16) short As[128 * 32];
    __shared__ __align__(16) short Bs[128 * 32];
    const int tid = threadIdx.x;
    const int lane = tid & 63;
    const int wave = tid >> 6;
    const int m0 = blockIdx.x * 128;  // co
    const int n0 = blockIdx.y * 128;  // l
    const int b = blockIdx.z;
    const bf16* xb = xpT + (size_t)b * PADL * CF;

    const int srow0 = wave * 32;
    const int lrow = lane >> 2;
    const int lcol = (lane & 3) * 8;
    short* aL0 = &As[srow0 * 32];
    short* aL1 = &As[(srow0 + 16) * 32];
    short* bL0 = &Bs[srow0 * 32];
    short* bL1 = &Bs[(srow0 + 16) * 32];

    const int wm = (wave & 1) * 64, wn = (wave >> 1) * 64;
    const int fr = lane & 15, quad = lane >> 4;

    floatx4 acc[4][4];
    #pragma unroll
    for (int i = 0; i < 4; i++)
        #pragma unroll
        for (int j = 0; j < 4; j++) acc[i][j] = (floatx4){0.f, 0.f, 0.f, 0.f};

    for (int tap = 0; tap < 3; tap++) {
        const bf16* aB = Wc + (size_t)tap * CF * CF;
        const bf16* aP0 = aB + (size_t)(m0 + srow0 + lrow) * CF + lcol;
        const bf16* aP1 = aB + (size_t)(m0 + srow0 + 16 + lrow) * CF + lcol;
        const bf16* bP0 = xb + (size_t)(n0 + srow0 + lrow + tap) * CF + lcol;
        const bf16* bP1 = xb + (size_t)(n0 + srow0 + 16 + lrow + tap) * CF + lcol;
        for (int k0 = 0; k0 < CF; k0 += 32) {
            gl_lds16(aP0 + k0, aL0);
            gl_lds16(aP1 + k0, aL1);
            gl_lds16(bP0 + k0, bL0);
            gl_lds16(bP1 + k0, bL1);
            __syncthreads();
            short8 af[4], bfv[4];
            #pragma unroll
            for (int i = 0; i < 4; i++) af[i] = *(const short8*)&As[(wm + i * 16 + fr) * 32 + quad * 8];
            #pragma unroll
            for (int j = 0; j < 4; j++) bfv[j] = *(const short8*)&Bs[(wn + j * 16 + fr) * 32 + quad * 8];
            #pragma unroll
            for (int i = 0; i < 4; i++)
                #pragma unroll
                for (int j = 0; j < 4; j++)
                    acc[i][j] = __builtin_amdgcn_mfma_f32_16x16x32_bf16(af[i], bfv[j], acc[i][j], 0, 0, 0);
            __syncthreads();
        }
    }
    bf16* ob = Out + (size_t)b * CF * CT2;
    #pragma unroll
    for (int i = 0; i < 4; i++) {
        int mb = m0 + wm + i * 16 + quad * 4;
        #pragma unroll
        for (int r = 0; r < 4; r++) {
            float bv = bias[mb + r];
            #pragma unroll
            for (int j = 0; j < 4; j++) {
                int n = n0 + wn + j * 16 + fr;
                float v = acc[i][j][r] + bv;
                ob[(size_t)(mb + r) * CT2 + n] = f2b(silu_f(v));
            }
        }
    }
}

// ---------------- xp (b,ci,l) -> xpT (b, l+1, ci) transposed, bf16 ----------------
__global__ __launch_bounds__(256) void xpt_kernel(const bf16* __restrict__ xp,
                                                  bf16* __restrict__ xpT) {
    __shared__ bf16 Ts[64][65];
    int b = blockIdx.z, ci0 = blockIdx.y * 64, l0 = blockIdx.x * 64;
    const bf16* src = xp + (size_t)b * CF * CT2;
    bf16* dst = xpT + (size_t)b * PADL * CF;
    for (int e = threadIdx.x; e < 4096; e += 256) {
        int r = e >> 6, c = e & 63;  // r: ci, c: l
        Ts[r][c] = src[(size_t)(ci0 + r) * CT2 + l0 + c];
    }
    __syncthreads();
    for (int e = threadIdx.x; e < 4096; e += 256) {
        int r = e >> 6, c = e & 63;  // r: l, c: ci
        dst[(size_t)(l0 + r + 1) * CF + ci0 + c] = Ts[c][r];
    }
}

__global__ void padzero_kernel(bf16* __restrict__ xpT) {
    int idx = blockIdx.x * 256 + threadIdx.x;  // 32 * 2 * 512
    int ci = idx & 511;
    int w = (idx >> 9) & 1;
    int b = idx >> 10;
    xpT[(size_t)b * PADL * CF + (w ? (size_t)(PADL - 1) * CF : 0) + ci] = f2b(0.0f);
}

// ---------------- cb[row] = dot(Bmat[row,:], Cmat[row,:]) over 256, bf16 in ----------
__global__ void cb_kernel(const bf16* __restrict__ Bm, const bf16* __restrict__ Cm,
                          float* __restrict__ cb) {
    int row = blockIdx.x;
    int lane = threadIdx.x;  // 64
    const bf16* bp = Bm + (size_t)row * CT + lane * 4;
    const bf16* cp = Cm + (size_t)row * CT + lane * 4;
    float s = 0.f;
    #pragma unroll
    for (int j = 0; j < 4; j++) s += b2f(bp[j]) * b2f(cp[j]);
    #pragma unroll
    for (int o = 32; o > 0; o >>= 1) s += __shfl_down(s, o);
    if (lane == 0) cb[row] = s;
}

// ---------------- s6 gate: P = silu(softplus(P) * xco * cb[row]) * xres --------------
__global__ void s6_gate_kernel(bf16* __restrict__ P, const bf16* __restrict__ xco,
                               const float* __restrict__ cbv, const bf16* __restrict__ xres) {
    int idx = blockIdx.x * blockDim.x + threadIdx.x;
    if (idx >= CB_ * CF * CT2) return;
    int row = idx >> 9;
    float delta = softplus_f(b2f(P[idx]));
    float xssm = delta * b2f(xco[idx]) * cbv[row];
    P[idx] = f2b(silu_f(xssm) * b2f(xres[idx]));
}

// ---------------- final: out[b,t,n] = DEC[b,n,t]*stdev + means (fp32 out) ------------
__global__ void out_kernel(const bf16* __restrict__ DEC, const float* __restrict__ means,
                           const float* __restrict__ stdev, float* __restrict__ out) {
    int idx = blockIdx.x * blockDim.x + threadIdx.x;
    if (idx >= CB_ * CT * CN) return;
    int n = idx % CN;
    int bt = idx / CN;
    int t = bt & (CT - 1);
    int b = bt >> 8;
    int sn = b * CN + n;
    out[idx] = b2f(DEC[(size_t)b * CF * CT + (size_t)n * CT + t]) * stdev[sn] + means[sn];
}

extern "C" void kernel_launch(void* const* d_in, const int* in_sizes, int n_in,
                              void* d_out, int out_size, void* d_ws, size_t ws_size,
                              hipStream_t stream) {
    const float* x_enc  = (const float*)d_in[0];
    const float* x_mark = (const float*)d_in[1];
    const float* norm_w = (const float*)d_in[4];
    const float* inp_W  = (const float*)d_in[5];
    const float* inp_b  = (const float*)d_in[6];
    const float* conv_W = (const float*)d_in[7];
    const float* conv_b = (const float*)d_in[8];
    const float* convlin_W = (const float*)d_in[9];
    const float* convlin_b = (const float*)d_in[10];
    const float* fc1_W = (const float*)d_in[11];
    const float* fc1_b = (const float*)d_in[12];
    const float* fc2_W = (const float*)d_in[13];
    const float* fc2_b = (const float*)d_in[14];
    const float* fc3_W = (const float*)d_in[15];
    const float* fc3_b = (const float*)d_in[16];
    const float* D_W   = (const float*)d_in[17];
    const float* D_b   = (const float*)d_in[18];
    const float* out_W = (const float*)d_in[19];
    const float* out_b = (const float*)d_in[20];
    const float* proj_W = (const float*)d_in[21];
    const float* proj_b = (const float*)d_in[22];

    // ---- workspace layout (total ~80 MB) ----
    char* ws = (char*)d_ws;
    float* CBv   = (float*)(ws);             // 64 KB used
    float* MEANS = (float*)(ws + 65536);
    float* STDEV = (float*)(ws + 131072);
    bf16* wt = (bf16*)(ws + 196608);         // transposed-weight arena (bf16 elem offsets):
    bf16* wt_inp     = wt;                   // 3 x [512][256]
    bf16* wt_convlin = wt + 393216;          // 3 x [512][512]
    bf16* wt_D       = wt + 1179648;         // 3 x [512][256]
    bf16* wt_fc1     = wt + 1572864;         // 3 x [512][512]
    bf16* wt_fc2     = wt + 2359296;         // 3 x [256][512]
    bf16* wt_fc3     = wt + 2752512;         // 3 x [256][512]
    bf16* wt_out     = wt + 3145728;         // 3 x [256][512]
    bf16* wt_conv    = wt + 3538944;         // 3 x [3][512][512]
    bf16* wt_proj    = wt + 5898240;         // [256][256]  (ends at 5963776 elems)
    bf16* xpT = (bf16*)(ws + 12582912);      // [32][514][512] bf16 = 16.84 MB
    const size_t POOLB = 16777216;           // bf16 pool bytes: 16384 x 512 x 2
    const size_t HALF = 16384 * 256;         // element offset of pool hi half
    bf16* pool[3] = {
        (bf16*)(ws + 29425664),
        (bf16*)(ws + 29425664 + POOLB),
        (bf16*)(ws + 29425664 + 2 * POOLB),
    };
    float* out = (float*)d_out;

    // ---- weight prepack (fp32 -> transposed bf16) ----
    wt_kernel<<<dim3(16, 8, 3), 256, 0, stream>>>(inp_W, wt_inp, 256, 512);
    wt_kernel<<<dim3(16, 16, 3), 256, 0, stream>>>(convlin_W, wt_convlin, 512, 512);
    wt_kernel<<<dim3(16, 8, 3), 256, 0, stream>>>(D_W, wt_D, 256, 512);
    wt_kernel<<<dim3(16, 16, 3), 256, 0, stream>>>(fc1_W, wt_fc1, 512, 512);
    wt_kernel<<<dim3(8, 16, 3), 256, 0, stream>>>(fc2_W, wt_fc2, 512, 256);
    wt_kernel<<<dim3(8, 16, 3), 256, 0, stream>>>(fc3_W, wt_fc3, 512, 256);
    wt_kernel<<<dim3(8, 16, 3), 256, 0, stream>>>(out_W, wt_out, 512, 256);
    wt_kernel<<<dim3(8, 8, 1), 256, 0, stream>>>(proj_W, wt_proj, 256, 256);
    convpack_kernel<<<9216, 256, 0, stream>>>(conv_W, wt_conv);

    // ---- stats + input construction: x -> pool[0].lo ----
    stats_kernel<<<(CB_ * CN + 255) / 256, 256, 0, stream>>>(x_enc, MEANS, STDEV);
    build_x_kernel<<<(CB_ * CF * CT) / 256, 256, 0, stream>>>(x_enc, x_mark, MEANS, STDEV, pool[0]);

    for (int i = 0; i < 3; i++) {
        bf16* A  = pool[i % 3];         // x(lo), xn(hi) -> Bmat/Cmat -> P/gate (full)
        bf16* Bp = pool[(i + 1) % 3];   // xp -> xco -> x_next(lo)
        bf16* Cp = pool[(i + 2) % 3];   // xc -> xres
        bf16* X  = A;
        bf16* XN = A + HALF;

        rmsnorm_kernel<<<MROWS, 256, 0, stream>>>(X, norm_w + i * CT, XN);
        // xp = xn @ inp_W + b  (M=16384, K=256, N=512) -> Bp
        mgemm_kernel<0><<<dim3(128, 4), 256, 0, stream>>>(XN, wt_inp + (size_t)i * 131072,
                                                          inp_b + i * CT2, Bp, 256, CT2);
        // transpose + pad for conv
        xpt_kernel<<<dim3(8, 8, CB_), 256, 0, stream>>>(Bp, xpT);
        padzero_kernel<<<128, 256, 0, stream>>>(xpT);
        // xc = silu(conv(xp)) -> Cp
        conv_mfma_kernel<<<dim3(4, 4, CB_), 256, 0, stream>>>(wt_conv + (size_t)i * 786432, xpT,
                                                              conv_b + i * CF, Cp);
        // xco = xc @ convlin + b -> Bp
        mgemm_kernel<0><<<dim3(128, 4), 256, 0, stream>>>(Cp, wt_convlin + (size_t)i * 262144,
                                                          convlin_b + i * CT2, Bp, 512, CT2);
        // xres = silu(xn @ D_W + b) -> Cp
        mgemm_kernel<1><<<dim3(128, 4), 256, 0, stream>>>(XN, wt_D + (size_t)i * 131072,
                                                          D_b + i * CT2, Cp, 256, CT2);
        // Bmat = xco @ fc2 + b -> A.lo ; Cmat = xco @ fc3 + b -> A.hi
        mgemm_kernel<0><<<dim3(128, 2), 256, 0, stream>>>(Bp, wt_fc2 + (size_t)i * 131072,
                                                          fc2_b + i * CT, X, 512, CT);
        mgemm_kernel<0><<<dim3(128, 2), 256, 0, stream>>>(Bp, wt_fc3 + (size_t)i * 131072,
                                                          fc3_b + i * CT, XN, 512, CT);
        cb_kernel<<<MROWS, 64, 0, stream>>>(X, XN, CBv);
        // P = xco @ fc1 + b -> A (full)
        mgemm_kernel<0><<<dim3(128, 4), 256, 0, stream>>>(Bp, wt_fc1 + (size_t)i * 262144,
                                                          fc1_b + i * CT2, A, 512, CT2);
        // gate in-place on A
        s6_gate_kernel<<<(CB_ * CF * CT2) / 256, 256, 0, stream>>>(A, Bp, CBv, Cp);
        // x_next = gate @ out_W + b -> Bp.lo
        mgemm_kernel<0><<<dim3(128, 2), 256, 0, stream>>>(A, wt_out + (size_t)i * 131072,
                                                          out_b + i * CT, Bp, 512, CT);
    }

    // dec = x @ proj_W + b -> pool[1] (16384 x 256)
    mgemm_kernel<0><<<dim3(128, 2), 256, 0, stream>>>(pool[0], wt_proj, proj_b, pool[1], 256, CT);
    out_kernel<<<(CB_ * CT * CN + 255) / 256, 256, 0, stream>>>(pool[1], MEANS, STDEV, out);
}

// Round 5
// 706.538 us; speedup vs baseline: 5.6574x; 1.1872x over previous
//
#include <hip/hip_runtime.h>
#include <hip/hip_bf16.h>
#include <math.h>

typedef __hip_bfloat16 bf16;
typedef short short8 __attribute__((ext_vector_type(8)));
typedef short short4v __attribute__((ext_vector_type(4)));
typedef float floatx4 __attribute__((ext_vector_type(4)));

// Problem constants
constexpr int CB_ = 32;    // batch
constexpr int CT = 256;    // T
constexpr int CF = 512;    // F
constexpr int CN = 508;    // N = F - M
constexpr int CM = 4;      // time-mark feats
constexpr int CT2 = 512;   // 2T
constexpr int MROWS = CB_ * CF;  // 16384
constexpr int PADL = 528;  // xpT padded row count per batch (rows 1..512 live, 0/513 zero, 514..527 slack)

__device__ __forceinline__ float b2f(bf16 v) { return __bfloat162float(v); }
__device__ __forceinline__ bf16 f2b(float v) { return __float2bfloat16(v); }
__device__ __forceinline__ float silu_f(float x) { return x / (1.0f + expf(-x)); }
__device__ __forceinline__ float softplus_f(float x) {
    return fmaxf(x, 0.0f) + log1pf(expf(-fabsf(x)));
}

__device__ __forceinline__ void gl_lds16(const bf16* g, short* l) {
    __builtin_amdgcn_global_load_lds(
        (const __attribute__((address_space(1))) unsigned int*)(g),
        (__attribute__((address_space(3))) unsigned int*)(l), 16, 0, 0);
}

// ---- weight prepack: W (K x N fp32, z-stride K*N) -> dst (N x K bf16, z-stride dstride)
__global__ __launch_bounds__(256) void wt_kernel(const float* __restrict__ src,
                                                 bf16* __restrict__ dst, int K, int N,
                                                 int dstride) {
    __shared__ float Ts[32][33];
    int n0 = blockIdx.x * 32, k0 = blockIdx.y * 32;
    const float* s = src + (size_t)blockIdx.z * K * N;
    bf16* d = dst + (size_t)blockIdx.z * dstride;
    for (int e = threadIdx.x; e < 1024; e += 256) {
        int r = e >> 5, c = e & 31;  // r: k, c: n
        Ts[r][c] = s[(size_t)(k0 + r) * N + n0 + c];
    }
    __syncthreads();
    for (int e = threadIdx.x; e < 1024; e += 256) {
        int r = e >> 5, c = e & 31;  // r: n, c: k
        d[(size_t)(n0 + r) * K + k0 + c] = f2b(Ts[c][r]);
    }
}

// ---- conv weight pack: src [3][co][ci][tap] fp32 -> dst [3][tap][co][ci] bf16
__global__ void convpack_kernel(const float* __restrict__ src, bf16* __restrict__ dst) {
    int idx = blockIdx.x * 256 + threadIdx.x;  // 3*3*512*512
    int ci = idx & 511;
    int co = (idx >> 9) & 511;
    int it = idx >> 18;        // ib*3 + tap
    int tap = it % 3, ib = it / 3;
    dst[idx] = f2b(src[(((size_t)(ib * 512 + co)) * 512 + ci) * 3 + tap]);
}

// ---- stats: per (b,n) mean/stdev over T ----
__global__ void stats_kernel(const float* __restrict__ xe, float* __restrict__ means,
                             float* __restrict__ stdev) {
    int idx = blockIdx.x * blockDim.x + threadIdx.x;
    if (idx >= CB_ * CN) return;
    int b = idx / CN, n = idx - b * CN;
    const float* p = xe + (size_t)b * CT * CN + n;
    float s = 0.f;
    for (int t = 0; t < CT; t++) s += p[t * CN];
    float mean = s * (1.0f / CT);
    float v = 0.f;
    for (int t = 0; t < CT; t++) {
        float d = p[t * CN] - mean;
        v += d * d;
    }
    v *= (1.0f / CT);
    means[idx] = mean;
    stdev[idx] = sqrtf(v + 1e-5f);
}

// ---- build X: (B, F, T) bf16 ----
__global__ void build_x_kernel(const float* __restrict__ xe, const float* __restrict__ xm,
                               const float* __restrict__ means, const float* __restrict__ stdev,
                               bf16* __restrict__ X) {
    int idx = blockIdx.x * blockDim.x + threadIdx.x;
    if (idx >= CB_ * CF * CT) return;
    int t = idx & (CT - 1);
    int f = (idx >> 8) & (CF - 1);
    int b = idx >> 17;
    float val;
    if (f < CN) {
        int sn = b * CN + f;
        val = (xe[(size_t)b * CT * CN + t * CN + f] - means[sn]) / stdev[sn];
    } else {
        val = xm[(size_t)b * CT * CM + t * CM + (f - CN)];
    }
    X[idx] = f2b(val);
}

// ---- rmsnorm over last dim (256) ----
__global__ __launch_bounds__(256) void rmsnorm_kernel(const bf16* __restrict__ X,
                                                      const float* __restrict__ nw,
                                                      bf16* __restrict__ XN) {
    __shared__ float red[4];
    int row = blockIdx.x;
    int t = threadIdx.x;
    float v = b2f(X[(size_t)row * CT + t]);
    float ss = v * v;
    #pragma unroll
    for (int o = 32; o > 0; o >>= 1) ss += __shfl_down(ss, o);
    if ((t & 63) == 0) red[t >> 6] = ss;
    __syncthreads();
    float total = red[0] + red[1] + red[2] + red[3];
    float scale = rsqrtf(total * (1.0f / CT) + 1e-5f);
    XN[(size_t)row * CT + t] = f2b(v * scale * nw[t]);
}

// ---- MFMA GEMM, m97 structure. MODE 0: plain o1 (stride Ncols), bias b1.
// MODE 1 ([inp|D], N=1024): n<512 -> write TRANSPOSED into xpT(o1) w/ bias b1;
//                           n>=512 -> silu(v+b2[n-512]) -> o2 (stride 512).
// MODE 3 ([fc1|fc2|fc3], N=1024): n<512 -> o1=P (stride 512, b1);
//                           n>=512 -> o2 col n-512 (stride 512, b2/b3).
template <int MODE>
__global__ __launch_bounds__(256) void mgemm_kernel(const bf16* __restrict__ A,
                                                    const bf16* __restrict__ Wt,
                                                    const float* __restrict__ b1,
                                                    const float* __restrict__ b2,
                                                    const float* __restrict__ b3,
                                                    bf16* __restrict__ o1,
                                                    bf16* __restrict__ o2,
                                                    int K, int Ncols) {
    __shared__ __align__(16) short As[128 * 32];
    __shared__ __align__(16) short Bs[128 * 32];
    const int tid = threadIdx.x;
    const int lane = tid & 63;
    const int wave = tid >> 6;
    const int m0 = blockIdx.x * 128, n0 = blockIdx.y * 128;

    const int srow0 = wave * 32;
    const int lrow = lane >> 2;
    const int lcol = (lane & 3) * 8;

    const bf16* aP0 = A + (size_t)(m0 + srow0 + lrow) * K + lcol;
    const bf16* aP1 = A + (size_t)(m0 + srow0 + 16 + lrow) * K + lcol;
    const bf16* bP0 = Wt + (size_t)(n0 + srow0 + lrow) * K + lcol;
    const bf16* bP1 = Wt + (size_t)(n0 + srow0 + 16 + lrow) * K + lcol;
    short* aL0 = &As[srow0 * 32];
    short* aL1 = &As[(srow0 + 16) * 32];
    short* bL0 = &Bs[srow0 * 32];
    short* bL1 = &Bs[(srow0 + 16) * 32];

    const int wm = (wave & 1) * 64, wn = (wave >> 1) * 64;
    const int fr = lane & 15, quad = lane >> 4;

    floatx4 acc[4][4];
    #pragma unroll
    for (int i = 0; i < 4; i++)
        #pragma unroll
        for (int j = 0; j < 4; j++) acc[i][j] = (floatx4){0.f, 0.f, 0.f, 0.f};

    for (int k0 = 0; k0 < K; k0 += 32) {
        gl_lds16(aP0 + k0, aL0);
        gl_lds16(aP1 + k0, aL1);
        gl_lds16(bP0 + k0, bL0);
        gl_lds16(bP1 + k0, bL1);
        __syncthreads();
        short8 af[4], bfv[4];
        #pragma unroll
        for (int i = 0; i < 4; i++) af[i] = *(const short8*)&As[(wm + i * 16 + fr) * 32 + quad * 8];
        #pragma unroll
        for (int j = 0; j < 4; j++) bfv[j] = *(const short8*)&Bs[(wn + j * 16 + fr) * 32 + quad * 8];
        #pragma unroll
        for (int i = 0; i < 4; i++)
            #pragma unroll
            for (int j = 0; j < 4; j++)
                acc[i][j] = __builtin_amdgcn_mfma_f32_16x16x32_bf16(af[i], bfv[j], acc[i][j], 0, 0, 0);
        __syncthreads();
    }

    if (MODE == 0) {
        #pragma unroll
        for (int j = 0; j < 4; j++) {
            int n = n0 + wn + j * 16 + fr;
            float bv = b1[n];
            #pragma unroll
            for (int i = 0; i < 4; i++) {
                int mb = m0 + wm + i * 16 + quad * 4;
                #pragma unroll
                for (int r = 0; r < 4; r++)
                    o1[(size_t)(mb + r) * Ncols + n] = f2b(acc[i][j][r] + bv);
            }
        }
    } else if (MODE == 1) {
        if (n0 + wn < 512) {
            // xp half: write transposed into xpT[b][n+1][ci], packed 4x bf16
            int b = (m0 + wm) >> 9;
            #pragma unroll
            for (int j = 0; j < 4; j++) {
                int n = n0 + wn + j * 16 + fr;
                float bv = b1[n];
                bf16* dst = o1 + ((size_t)b * PADL + n + 1) * 512;
                #pragma unroll
                for (int i = 0; i < 4; i++) {
                    int ci = (m0 + wm + i * 16 + quad * 4) & 511;
                    short4v pk;
                    #pragma unroll
                    for (int r = 0; r < 4; r++) {
                        bf16 t = f2b(acc[i][j][r] + bv);
                        pk[r] = __builtin_bit_cast(short, t);
                    }
                    *(short4v*)(dst + ci) = pk;
                }
            }
        } else {
            // xres half: silu, normal layout, stride 512
            #pragma unroll
            for (int j = 0; j < 4; j++) {
                int n = n0 + wn + j * 16 + fr;
                float bv = b2[n - 512];
                #pragma unroll
                for (int i = 0; i < 4; i++) {
                    int mb = m0 + wm + i * 16 + quad * 4;
                    #pragma unroll
                    for (int r = 0; r < 4; r++)
                        o2[(size_t)(mb + r) * 512 + (n - 512)] = f2b(silu_f(acc[i][j][r] + bv));
                }
            }
        }
    } else {  // MODE 3
        if (n0 + wn < 512) {
            #pragma unroll
            for (int j = 0; j < 4; j++) {
                int n = n0 + wn + j * 16 + fr;
                float bv = b1[n];
                #pragma unroll
                for (int i = 0; i < 4; i++) {
                    int mb = m0 + wm + i * 16 + quad * 4;
                    #pragma unroll
                    for (int r = 0; r < 4; r++)
                        o1[(size_t)(mb + r) * 512 + n] = f2b(acc[i][j][r] + bv);
                }
            }
        } else {
            #pragma unroll
            for (int j = 0; j < 4; j++) {
                int n = n0 + wn + j * 16 + fr;
                float bv = (n < 768) ? b2[n - 512] : b3[n - 768];
                #pragma unroll
                for (int i = 0; i < 4; i++) {
                    int mb = m0 + wm + i * 16 + quad * 4;
                    #pragma unroll
                    for (int r = 0; r < 4; r++)
                        o2[(size_t)(mb + r) * 512 + (n - 512)] = f2b(acc[i][j][r] + bv);
                }
            }
        }
    }
}

// ---- conv as implicit MFMA GEMM: single B-stage for all 3 taps + XCD swizzle ----
// Out[b,co,l] = silu( sum_tap sum_ci Wc[tap][co][ci] * xpT[b][l+tap][ci] + bias[co] )
__global__ __launch_bounds__(256) void conv_mfma_kernel(const bf16* __restrict__ Wc,
                                                        const bf16* __restrict__ xpT,
                                                        const float* __restrict__ bias,
                                                        bf16* __restrict__ Out) {
    __shared__ __align__(16) short As[3 * 128 * 32];  // [tap][row][k] 24.6 KB
    __shared__ __align__(16) short Bs[144 * 32];      // rows n0..n0+143   9.2 KB
    const int tid = threadIdx.x;
    const int lane = tid & 63;
    const int wave = tid >> 6;
    // XCD swizzle: each XCD handles all 4 m-tiles x 16 (n,b) pairs -> weights+x L2-resident
    int bx = blockIdx.x;                  // 512 blocks
    int xcd = bx & 7, g = bx >> 3;
    int mt = g & 3;
    int id = xcd * 16 + (g >> 2);         // 0..127 (n,b) pair
    int nt = id & 3, b = id >> 2;
    const int m0 = mt * 128, n0 = nt * 128;
    const bf16* xb = xpT + (size_t)b * PADL * 512;

    const int lrow = lane >> 2;
    const int lcol = (lane & 3) * 8;
    const int wm = (wave & 1) * 64, wn = (wave >> 1) * 64;
    const int fr = lane & 15, quad = lane >> 4;

    floatx4 acc[4][4];
    #pragma unroll
    for (int i = 0; i < 4; i++)
        #pragma unroll
        for (int j = 0; j < 4; j++) acc[i][j] = (floatx4){0.f, 0.f, 0.f, 0.f};

    for (int k0 = 0; k0 < 512; k0 += 32) {
        // stage A: 24 granules of 16 rows (3 taps x 128 rows)
        for (int ga = wave; ga < 24; ga += 4) {
            int tap = ga >> 3, rg = ga & 7;
            gl_lds16(Wc + (size_t)tap * 262144 + (size_t)(m0 + rg * 16 + lrow) * 512 + k0 + lcol,
                     &As[ga * 512]);
        }
        // stage B: 9 granules (144 rows, covers taps 0..2)
        for (int gb = wave; gb < 9; gb += 4) {
            gl_lds16(xb + (size_t)(n0 + gb * 16 + lrow) * 512 + k0 + lcol, &Bs[gb * 512]);
        }
        __syncthreads();
        #pragma unroll
        for (int tap = 0; tap < 3; tap++) {
            short8 af[4], bfv[4];
            #pragma unroll
            for (int i = 0; i < 4; i++)
                af[i] = *(const short8*)&As[tap * 4096 + (wm + i * 16 + fr) * 32 + quad * 8];
            #pragma unroll
            for (int j = 0; j < 4; j++)
                bfv[j] = *(const short8*)&Bs[(wn + j * 16 + fr + tap) * 32 + quad * 8];
            #pragma unroll
            for (int i = 0; i < 4; i++)
                #pragma unroll
                for (int j = 0; j < 4; j++)
                    acc[i][j] = __builtin_amdgcn_mfma_f32_16x16x32_bf16(af[i], bfv[j], acc[i][j], 0, 0, 0);
        }
        __syncthreads();
    }
    bf16* ob = Out + (size_t)b * CF * CT2;
    #pragma unroll
    for (int i = 0; i < 4; i++) {
        int mb = m0 + wm + i * 16 + quad * 4;
        #pragma unroll
        for (int r = 0; r < 4; r++) {
            float bv = bias[mb + r];
            #pragma unroll
            for (int j = 0; j < 4; j++) {
                int n = n0 + wn + j * 16 + fr;
                ob[(size_t)(mb + r) * CT2 + n] = f2b(silu_f(acc[i][j][r] + bv));
            }
        }
    }
}

// ---- zero xpT pad rows (0 and 513) for each batch ----
__global__ void padzero_kernel(bf16* __restrict__ xpT) {
    int idx = blockIdx.x * 256 + threadIdx.x;  // 32*2*512
    int ci = idx & 511;
    int w = (idx >> 9) & 1;
    int b = idx >> 10;
    xpT[((size_t)b * PADL + (w ? 513 : 0)) * 512 + ci] = f2b(0.0f);
}

// ---- fused cb + s6 gate: one block per row ----
// cb = dot(E[row,0:256], E[row,256:512]); P = silu(softplus(P)*xco*cb)*xres
__global__ __launch_bounds__(256) void gate_kernel(bf16* __restrict__ P,
                                                   const bf16* __restrict__ xco,
                                                   const bf16* __restrict__ E,
                                                   const bf16* __restrict__ xres) {
    __shared__ float red[4];
    int row = blockIdx.x;
    int t = threadIdx.x;
    size_t base = (size_t)row * 512;
    float s = b2f(E[base + t]) * b2f(E[base + 256 + t]);
    #pragma unroll
    for (int o = 32; o > 0; o >>= 1) s += __shfl_down(s, o);
    if ((t & 63) == 0) red[t >> 6] = s;
    __syncthreads();
    float cb = red[0] + red[1] + red[2] + red[3];
    #pragma unroll
    for (int h = 0; h < 2; h++) {
        size_t idx = base + t + h * 256;
        float delta = softplus_f(b2f(P[idx]));
        float xssm = delta * b2f(xco[idx]) * cb;
        P[idx] = f2b(silu_f(xssm) * b2f(xres[idx]));
    }
}

// ---- final: out[b,t,n] = DEC[b,n,t]*stdev + means (fp32 out) ----
__global__ void out_kernel(const bf16* __restrict__ DEC, const float* __restrict__ means,
                           const float* __restrict__ stdev, float* __restrict__ out) {
    int idx = blockIdx.x * blockDim.x + threadIdx.x;
    if (idx >= CB_ * CT * CN) return;
    int n = idx % CN;
    int bt = idx / CN;
    int t = bt & (CT - 1);
    int b = bt >> 8;
    int sn = b * CN + n;
    out[idx] = b2f(DEC[(size_t)b * CF * CT + (size_t)n * CT + t]) * stdev[sn] + means[sn];
}

extern "C" void kernel_launch(void* const* d_in, const int* in_sizes, int n_in,
                              void* d_out, int out_size, void* d_ws, size_t ws_size,
                              hipStream_t stream) {
    const float* x_enc  = (const float*)d_in[0];
    const float* x_mark = (const float*)d_in[1];
    const float* norm_w = (const float*)d_in[4];
    const float* inp_W  = (const float*)d_in[5];
    const float* inp_b  = (const float*)d_in[6];
    const float* conv_W = (const float*)d_in[7];
    const float* conv_b = (const float*)d_in[8];
    const float* convlin_W = (const float*)d_in[9];
    const float* convlin_b = (const float*)d_in[10];
    const float* fc1_W = (const float*)d_in[11];
    const float* fc1_b = (const float*)d_in[12];
    const float* fc2_W = (const float*)d_in[13];
    const float* fc2_b = (const float*)d_in[14];
    const float* fc3_W = (const float*)d_in[15];
    const float* fc3_b = (const float*)d_in[16];
    const float* D_W   = (const float*)d_in[17];
    const float* D_b   = (const float*)d_in[18];
    const float* out_W = (const float*)d_in[19];
    const float* out_b = (const float*)d_in[20];
    const float* proj_W = (const float*)d_in[21];
    const float* proj_b = (const float*)d_in[22];

    // ---- workspace layout (~92 MB) ----
    char* ws = (char*)d_ws;
    float* MEANS = (float*)(ws);             // 64 KB slot
    float* STDEV = (float*)(ws + 65536);
    bf16* wt = (bf16*)(ws + 131072);         // bf16 element offsets:
    bf16* wt_g1      = wt;                   // 3 x [1024][256]  (inp^T | D^T)
    bf16* wt_g3      = wt + 786432;          // 3 x [1024][512]  (fc1^T | fc2^T | fc3^T)
    bf16* wt_convlin = wt + 2359296;         // 3 x [512][512]
    bf16* wt_out     = wt + 3145728;         // 3 x [256][512]
    bf16* wt_proj    = wt + 3538944;         // [256][256]
    bf16* wt_conv    = wt + 3604480;         // 3 x [3][512][512]
    bf16* xpT = (bf16*)(ws + 12058624);      // [32][528][512] bf16 = 17.3 MB
    const size_t POOLB = 16777216;
    const size_t HALF = 16384 * 256;
    bf16* pool[3] = {
        (bf16*)(ws + 29360128),
        (bf16*)(ws + 29360128 + POOLB),
        (bf16*)(ws + 29360128 + 2 * POOLB),
    };
    bf16* E = (bf16*)(ws + 29360128 + 3 * POOLB);  // [16384][512]: Bmat|Cmat
    float* out = (float*)d_out;

    // ---- weight prepack ----
    wt_kernel<<<dim3(16, 8, 3), 256, 0, stream>>>(inp_W, wt_g1, 256, 512, 262144);
    wt_kernel<<<dim3(16, 8, 3), 256, 0, stream>>>(D_W, wt_g1 + 131072, 256, 512, 262144);
    wt_kernel<<<dim3(16, 16, 3), 256, 0, stream>>>(fc1_W, wt_g3, 512, 512, 524288);
    wt_kernel<<<dim3(8, 16, 3), 256, 0, stream>>>(fc2_W, wt_g3 + 262144, 512, 256, 524288);
    wt_kernel<<<dim3(8, 16, 3), 256, 0, stream>>>(fc3_W, wt_g3 + 393216, 512, 256, 524288);
    wt_kernel<<<dim3(16, 16, 3), 256, 0, stream>>>(convlin_W, wt_convlin, 512, 512, 262144);
    wt_kernel<<<dim3(8, 16, 3), 256, 0, stream>>>(out_W, wt_out, 512, 256, 131072);
    wt_kernel<<<dim3(8, 8, 1), 256, 0, stream>>>(proj_W, wt_proj, 256, 256, 65536);
    convpack_kernel<<<9216, 256, 0, stream>>>(conv_W, wt_conv);

    // ---- stats + input construction + pad init ----
    stats_kernel<<<(CB_ * CN + 255) / 256, 256, 0, stream>>>(x_enc, MEANS, STDEV);
    build_x_kernel<<<(CB_ * CF * CT) / 256, 256, 0, stream>>>(x_enc, x_mark, MEANS, STDEV, pool[0]);
    padzero_kernel<<<128, 256, 0, stream>>>(xpT);

    for (int i = 0; i < 3; i++) {
        bf16* A  = pool[i % 3];         // x(lo)+xn(hi) -> xc -> P/gate
        bf16* Bp = pool[(i + 1) % 3];   // xco -> x_next(lo)
        bf16* Cp = pool[(i + 2) % 3];   // xres
        bf16* X  = A;
        bf16* XN = A + HALF;

        rmsnorm_kernel<<<MROWS, 256, 0, stream>>>(X, norm_w + i * CT, XN);
        // [xp|xres] = xn @ [inp|D] + b : xp -> xpT (transposed), xres -> Cp
        mgemm_kernel<1><<<dim3(128, 8), 256, 0, stream>>>(
            XN, wt_g1 + (size_t)i * 262144, inp_b + i * CT2, D_b + i * CT2, nullptr,
            xpT, Cp, 256, 1024);
        // xc = silu(conv(xp)) -> A (x/xn dead)
        conv_mfma_kernel<<<512, 256, 0, stream>>>(wt_conv + (size_t)i * 786432, xpT,
                                                  conv_b + i * CF, A);
        // xco = xc @ convlin + b -> Bp
        mgemm_kernel<0><<<dim3(128, 4), 256, 0, stream>>>(
            A, wt_convlin + (size_t)i * 262144, convlin_b + i * CT2, nullptr, nullptr,
            Bp, nullptr, 512, 512);
        // [P|Bmat|Cmat] = xco @ [fc1|fc2|fc3] + b : P -> A, Bmat|Cmat -> E
        mgemm_kernel<3><<<dim3(128, 8), 256, 0, stream>>>(
            Bp, wt_g3 + (size_t)i * 524288, fc1_b + i * CT2, fc2_b + i * CT, fc3_b + i * CT,
            A, E, 512, 1024);
        // gate: P = silu(softplus(P)*xco*cb)*xres (in-place on A)
        gate_kernel<<<MROWS, 256, 0, stream>>>(A, Bp, E, Cp);
        // x_next = gate @ out_W + b -> Bp.lo
        mgemm_kernel<0><<<dim3(128, 2), 256, 0, stream>>>(
            A, wt_out + (size_t)i * 131072, out_b + i * CT, nullptr, nullptr,
            Bp, nullptr, 512, 256);
    }

    // dec = x @ proj_W + b -> pool[1] (16384 x 256)
    mgemm_kernel<0><<<dim3(128, 2), 256, 0, stream>>>(
        pool[0], wt_proj, proj_b, nullptr, nullptr, pool[1], nullptr, 256, 256);
    out_kernel<<<(CB_ * CT * CN + 255) / 256, 256, 0, stream>>>(pool[1], MEANS, STDEV, out);
}

// Round 6
// 640.983 us; speedup vs baseline: 6.2360x; 1.1023x over previous
//
#include <hip/hip_runtime.h>
#include <hip/hip_bf16.h>
#include <math.h>

typedef __hip_bfloat16 bf16;
typedef short short8 __attribute__((ext_vector_type(8)));
typedef short short4v __attribute__((ext_vector_type(4)));
typedef float floatx4 __attribute__((ext_vector_type(4)));

constexpr int CB_ = 32;
constexpr int CT = 256;
constexpr int CF = 512;
constexpr int CN = 508;
constexpr int CM = 4;
constexpr int CT2 = 512;
constexpr int MROWS = CB_ * CF;  // 16384
constexpr int PADL = 528;       // xpT rows/batch: 0 pad, 1..512 live, 513 pad, rest slack

__device__ __forceinline__ float b2f(bf16 v) { return __bfloat162float(v); }
__device__ __forceinline__ bf16 f2b(float v) { return __float2bfloat16(v); }
__device__ __forceinline__ float silu_f(float x) { return x / (1.0f + expf(-x)); }
__device__ __forceinline__ float softplus_f(float x) {
    return fmaxf(x, 0.0f) + log1pf(expf(-fabsf(x)));
}

__device__ __forceinline__ void gl_lds16(const bf16* g, short* l) {
    __builtin_amdgcn_global_load_lds(
        (const __attribute__((address_space(1))) unsigned int*)(g),
        (__attribute__((address_space(3))) unsigned int*)(l), 16, 0, 0);
}

// ---- merged weight prepack: 8 matrices, W(KxN fp32) -> Wt(NxK bf16) ----
struct P8 { const float* s[8]; bf16* d[8]; };
__global__ __launch_bounds__(256) void prepack_all_kernel(P8 p) {
    const int Ks[8]   = {256, 256, 512, 512, 512, 512, 512, 256};
    const int Ns[8]   = {512, 512, 512, 256, 256, 512, 256, 256};
    const int zs[8]   = {3, 3, 3, 3, 3, 3, 3, 1};
    const int dstr[8] = {262144, 262144, 524288, 524288, 524288, 262144, 131072, 65536};
    int bid = blockIdx.x;
    int m = 0, acc = 0;
    for (m = 0; m < 8; m++) {
        int c = (Ns[m] >> 5) * (Ks[m] >> 5) * zs[m];
        if (bid < acc + c) break;
        acc += c;
    }
    int lid = bid - acc;
    int K = Ks[m], N = Ns[m];
    int tx = N >> 5, ty = K >> 5;
    int z = lid / (tx * ty), rem = lid % (tx * ty);
    int k0 = (rem / tx) * 32, n0 = (rem % tx) * 32;
    const float* s = p.s[m] + (size_t)z * K * N;
    bf16* d = p.d[m] + (size_t)z * dstr[m];
    __shared__ float Ts[32][33];
    for (int e = threadIdx.x; e < 1024; e += 256) {
        int r = e >> 5, c = e & 31;
        Ts[r][c] = s[(size_t)(k0 + r) * N + n0 + c];
    }
    __syncthreads();
    for (int e = threadIdx.x; e < 1024; e += 256) {
        int r = e >> 5, c = e & 31;
        d[(size_t)(n0 + r) * K + k0 + c] = f2b(Ts[c][r]);
    }
}

// ---- conv weight pack + xpT pad-row zero (merged) ----
constexpr int CONVN = 3 * 3 * 512 * 512;  // 2359296
__global__ void convpack_kernel(const float* __restrict__ src, bf16* __restrict__ dst,
                                bf16* __restrict__ xpT) {
    int idx = blockIdx.x * 256 + threadIdx.x;
    if (idx < CONVN) {
        int ci = idx & 511;
        int co = (idx >> 9) & 511;
        int it = idx >> 18;
        int tap = it % 3, ib = it / 3;
        dst[idx] = f2b(src[(((size_t)(ib * 512 + co)) * 512 + ci) * 3 + tap]);
    } else if (idx < CONVN + 32768) {
        int j = idx - CONVN;  // b*1024 + w*512 + ci
        int ci = j & 511;
        int w = (j >> 9) & 1;
        int b = j >> 10;
        xpT[((size_t)b * PADL + (w ? 513 : 0)) * 512 + ci] = f2b(0.0f);
    }
}

// ---- fused stats + build_x + rmsnorm (iter 0): one block per row (b,f) ----
__global__ __launch_bounds__(256) void buildx_rms_kernel(
    const float* __restrict__ xe, const float* __restrict__ xm,
    const float* __restrict__ nw, float* __restrict__ means, float* __restrict__ stdev,
    bf16* __restrict__ XN) {
    __shared__ float rbuf[4];
    int row = blockIdx.x;
    int b = row >> 9, f = row & 511;
    int t = threadIdx.x;
    int lane = t & 63, wid = t >> 6;
    float val;
    if (f < CN) {
        float v = xe[(size_t)b * CT * CN + t * CN + f];
        float s = v;
        #pragma unroll
        for (int o = 32; o > 0; o >>= 1) s += __shfl_xor(s, o);
        if (lane == 0) rbuf[wid] = s;
        __syncthreads();
        float mean = (rbuf[0] + rbuf[1] + rbuf[2] + rbuf[3]) * (1.0f / CT);
        __syncthreads();
        float d = v - mean;
        float s2 = d * d;
        #pragma unroll
        for (int o = 32; o > 0; o >>= 1) s2 += __shfl_xor(s2, o);
        if (lane == 0) rbuf[wid] = s2;
        __syncthreads();
        float var = (rbuf[0] + rbuf[1] + rbuf[2] + rbuf[3]) * (1.0f / CT);
        __syncthreads();
        float sd = sqrtf(var + 1e-5f);
        if (t == 0) {
            means[b * CN + f] = mean;
            stdev[b * CN + f] = sd;
        }
        val = d / sd;
    } else {
        val = xm[(size_t)b * CT * CM + t * CM + (f - CN)];
    }
    // rmsnorm over the 256 cols
    float ss = val * val;
    #pragma unroll
    for (int o = 32; o > 0; o >>= 1) ss += __shfl_xor(ss, o);
    if (lane == 0) rbuf[wid] = ss;
    __syncthreads();
    float total = rbuf[0] + rbuf[1] + rbuf[2] + rbuf[3];
    float scale = rsqrtf(total * (1.0f / CT) + 1e-5f);
    XN[(size_t)row * CT + t] = f2b(val * scale * nw[t]);
}

// ---- MFMA GEMM (m97 structure). MODE 0: plain. MODE 1: [inp|D] split epilogue.
// MODE 3: [fc1|fc2|fc3] split epilogue.
template <int MODE>
__global__ __launch_bounds__(256) void mgemm_kernel(const bf16* __restrict__ A,
                                                    const bf16* __restrict__ Wt,
                                                    const float* __restrict__ b1,
                                                    const float* __restrict__ b2,
                                                    const float* __restrict__ b3,
                                                    bf16* __restrict__ o1,
                                                    bf16* __restrict__ o2,
                                                    int K, int Ncols) {
    __shared__ __align__(16) short As[128 * 32];
    __shared__ __align__(16) short Bs[128 * 32];
    const int tid = threadIdx.x;
    const int lane = tid & 63;
    const int wave = tid >> 6;
    const int m0 = blockIdx.x * 128, n0 = blockIdx.y * 128;

    const int srow0 = wave * 32;
    const int lrow = lane >> 2;
    const int lcol = (lane & 3) * 8;

    const bf16* aP0 = A + (size_t)(m0 + srow0 + lrow) * K + lcol;
    const bf16* aP1 = A + (size_t)(m0 + srow0 + 16 + lrow) * K + lcol;
    const bf16* bP0 = Wt + (size_t)(n0 + srow0 + lrow) * K + lcol;
    const bf16* bP1 = Wt + (size_t)(n0 + srow0 + 16 + lrow) * K + lcol;
    short* aL0 = &As[srow0 * 32];
    short* aL1 = &As[(srow0 + 16) * 32];
    short* bL0 = &Bs[srow0 * 32];
    short* bL1 = &Bs[(srow0 + 16) * 32];

    const int wm = (wave & 1) * 64, wn = (wave >> 1) * 64;
    const int fr = lane & 15, quad = lane >> 4;

    floatx4 acc[4][4];
    #pragma unroll
    for (int i = 0; i < 4; i++)
        #pragma unroll
        for (int j = 0; j < 4; j++) acc[i][j] = (floatx4){0.f, 0.f, 0.f, 0.f};

    for (int k0 = 0; k0 < K; k0 += 32) {
        gl_lds16(aP0 + k0, aL0);
        gl_lds16(aP1 + k0, aL1);
        gl_lds16(bP0 + k0, bL0);
        gl_lds16(bP1 + k0, bL1);
        __syncthreads();
        short8 af[4], bfv[4];
        #pragma unroll
        for (int i = 0; i < 4; i++) af[i] = *(const short8*)&As[(wm + i * 16 + fr) * 32 + quad * 8];
        #pragma unroll
        for (int j = 0; j < 4; j++) bfv[j] = *(const short8*)&Bs[(wn + j * 16 + fr) * 32 + quad * 8];
        #pragma unroll
        for (int i = 0; i < 4; i++)
            #pragma unroll
            for (int j = 0; j < 4; j++)
                acc[i][j] = __builtin_amdgcn_mfma_f32_16x16x32_bf16(af[i], bfv[j], acc[i][j], 0, 0, 0);
        __syncthreads();
    }

    if (MODE == 0) {
        #pragma unroll
        for (int j = 0; j < 4; j++) {
            int n = n0 + wn + j * 16 + fr;
            float bv = b1[n];
            #pragma unroll
            for (int i = 0; i < 4; i++) {
                int mb = m0 + wm + i * 16 + quad * 4;
                #pragma unroll
                for (int r = 0; r < 4; r++)
                    o1[(size_t)(mb + r) * Ncols + n] = f2b(acc[i][j][r] + bv);
            }
        }
    } else if (MODE == 1) {
        if (n0 + wn < 512) {
            int b = (m0 + wm) >> 9;
            #pragma unroll
            for (int j = 0; j < 4; j++) {
                int n = n0 + wn + j * 16 + fr;
                float bv = b1[n];
                bf16* dst = o1 + ((size_t)b * PADL + n + 1) * 512;
                #pragma unroll
                for (int i = 0; i < 4; i++) {
                    int ci = (m0 + wm + i * 16 + quad * 4) & 511;
                    short4v pk;
                    #pragma unroll
                    for (int r = 0; r < 4; r++) {
                        bf16 tb = f2b(acc[i][j][r] + bv);
                        pk[r] = __builtin_bit_cast(short, tb);
                    }
                    *(short4v*)(dst + ci) = pk;
                }
            }
        } else {
            #pragma unroll
            for (int j = 0; j < 4; j++) {
                int n = n0 + wn + j * 16 + fr;
                float bv = b2[n - 512];
                #pragma unroll
                for (int i = 0; i < 4; i++) {
                    int mb = m0 + wm + i * 16 + quad * 4;
                    #pragma unroll
                    for (int r = 0; r < 4; r++)
                        o2[(size_t)(mb + r) * 512 + (n - 512)] = f2b(silu_f(acc[i][j][r] + bv));
                }
            }
        }
    } else {  // MODE 3
        if (n0 + wn < 512) {
            #pragma unroll
            for (int j = 0; j < 4; j++) {
                int n = n0 + wn + j * 16 + fr;
                float bv = b1[n];
                #pragma unroll
                for (int i = 0; i < 4; i++) {
                    int mb = m0 + wm + i * 16 + quad * 4;
                    #pragma unroll
                    for (int r = 0; r < 4; r++)
                        o1[(size_t)(mb + r) * 512 + n] = f2b(acc[i][j][r] + bv);
                }
            }
        } else {
            #pragma unroll
            for (int j = 0; j < 4; j++) {
                int n = n0 + wn + j * 16 + fr;
                float bv = (n < 768) ? b2[n - 512] : b3[n - 768];
                #pragma unroll
                for (int i = 0; i < 4; i++) {
                    int mb = m0 + wm + i * 16 + quad * 4;
                    #pragma unroll
                    for (int r = 0; r < 4; r++)
                        o2[(size_t)(mb + r) * 512 + (n - 512)] = f2b(acc[i][j][r] + bv);
                }
            }
        }
    }
}

// ---- conv as implicit MFMA GEMM: single B-stage for all 3 taps + XCD swizzle ----
__global__ __launch_bounds__(256) void conv_mfma_kernel(const bf16* __restrict__ Wc,
                                                        const bf16* __restrict__ xpT,
                                                        const float* __restrict__ bias,
                                                        bf16* __restrict__ Out) {
    __shared__ __align__(16) short As[3 * 128 * 32];
    __shared__ __align__(16) short Bs[144 * 32];
    const int tid = threadIdx.x;
    const int lane = tid & 63;
    const int wave = tid >> 6;
    int bx = blockIdx.x;
    int xcd = bx & 7, g = bx >> 3;
    int mt = g & 3;
    int id = xcd * 16 + (g >> 2);
    int nt = id & 3, b = id >> 2;
    const int m0 = mt * 128, n0 = nt * 128;
    const bf16* xb = xpT + (size_t)b * PADL * 512;

    const int lrow = lane >> 2;
    const int lcol = (lane & 3) * 8;
    const int wm = (wave & 1) * 64, wn = (wave >> 1) * 64;
    const int fr = lane & 15, quad = lane >> 4;

    floatx4 acc[4][4];
    #pragma unroll
    for (int i = 0; i < 4; i++)
        #pragma unroll
        for (int j = 0; j < 4; j++) acc[i][j] = (floatx4){0.f, 0.f, 0.f, 0.f};

    for (int k0 = 0; k0 < 512; k0 += 32) {
        for (int ga = wave; ga < 24; ga += 4) {
            int tap = ga >> 3, rg = ga & 7;
            gl_lds16(Wc + (size_t)tap * 262144 + (size_t)(m0 + rg * 16 + lrow) * 512 + k0 + lcol,
                     &As[ga * 512]);
        }
        for (int gb = wave; gb < 9; gb += 4) {
            gl_lds16(xb + (size_t)(n0 + gb * 16 + lrow) * 512 + k0 + lcol, &Bs[gb * 512]);
        }
        __syncthreads();
        #pragma unroll
        for (int tap = 0; tap < 3; tap++) {
            short8 af[4], bfv[4];
            #pragma unroll
            for (int i = 0; i < 4; i++)
                af[i] = *(const short8*)&As[tap * 4096 + (wm + i * 16 + fr) * 32 + quad * 8];
            #pragma unroll
            for (int j = 0; j < 4; j++)
                bfv[j] = *(const short8*)&Bs[(wn + j * 16 + fr + tap) * 32 + quad * 8];
            #pragma unroll
            for (int i = 0; i < 4; i++)
                #pragma unroll
                for (int j = 0; j < 4; j++)
                    acc[i][j] = __builtin_amdgcn_mfma_f32_16x16x32_bf16(af[i], bfv[j], acc[i][j], 0, 0, 0);
        }
        __syncthreads();
    }
    bf16* ob = Out + (size_t)b * CF * CT2;
    #pragma unroll
    for (int i = 0; i < 4; i++) {
        int mb = m0 + wm + i * 16 + quad * 4;
        #pragma unroll
        for (int r = 0; r < 4; r++) {
            float bv = bias[mb + r];
            #pragma unroll
            for (int j = 0; j < 4; j++) {
                int n = n0 + wn + j * 16 + fr;
                ob[(size_t)(mb + r) * CT2 + n] = f2b(silu_f(acc[i][j][r] + bv));
            }
        }
    }
}

// ---- fused cb + s6 gate ----
__global__ __launch_bounds__(256) void gate_kernel(bf16* __restrict__ P,
                                                   const bf16* __restrict__ xco,
                                                   const bf16* __restrict__ E,
                                                   const bf16* __restrict__ xres) {
    __shared__ float red[4];
    int row = blockIdx.x;
    int t = threadIdx.x;
    size_t base = (size_t)row * 512;
    float s = b2f(E[base + t]) * b2f(E[base + 256 + t]);
    #pragma unroll
    for (int o = 32; o > 0; o >>= 1) s += __shfl_down(s, o);
    if ((t & 63) == 0) red[t >> 6] = s;
    __syncthreads();
    float cb = red[0] + red[1] + red[2] + red[3];
    #pragma unroll
    for (int h = 0; h < 2; h++) {
        size_t idx = base + t + h * 256;
        float delta = softplus_f(b2f(P[idx]));
        float xssm = delta * b2f(xco[idx]) * cb;
        P[idx] = f2b(silu_f(xssm) * b2f(xres[idx]));
    }
}

// ---- out-GEMM (K=512, N=256 full width) with FUSED rmsnorm epilogue ----
// Writes x_next (Xo) and xn = rmsnorm(x_next)*nw (XNo).
__global__ __launch_bounds__(256) void gemm_rms_kernel(const bf16* __restrict__ A,
                                                       const bf16* __restrict__ Wt,
                                                       const float* __restrict__ bias,
                                                       const float* __restrict__ nw,
                                                       bf16* __restrict__ Xo,
                                                       bf16* __restrict__ XNo) {
    __shared__ __align__(16) short As[64 * 32];
    __shared__ __align__(16) short Bs[256 * 32];
    __shared__ float red[4][64];
    __shared__ float scl[64];
    const int tid = threadIdx.x;
    const int lane = tid & 63;
    const int wave = tid >> 6;
    const int m0 = blockIdx.x * 64;

    const int lrow = lane >> 2;
    const int lcol = (lane & 3) * 8;
    // staging: wave stages A-granule [wave] and B-granules [4w..4w+3]
    const bf16* aP = A + (size_t)(m0 + wave * 16 + lrow) * 512 + lcol;
    short* aL = &As[wave * 16 * 32];
    const bf16* bP[4];
    short* bL[4];
    #pragma unroll
    for (int g = 0; g < 4; g++) {
        int r0 = (wave * 4 + g) * 16;
        bP[g] = Wt + (size_t)(r0 + lrow) * 512 + lcol;
        bL[g] = &Bs[r0 * 32];
    }
    const int wn = wave * 64;
    const int fr = lane & 15, quad = lane >> 4;

    floatx4 acc[4][4];
    #pragma unroll
    for (int i = 0; i < 4; i++)
        #pragma unroll
        for (int j = 0; j < 4; j++) acc[i][j] = (floatx4){0.f, 0.f, 0.f, 0.f};

    for (int k0 = 0; k0 < 512; k0 += 32) {
        gl_lds16(aP + k0, aL);
        #pragma unroll
        for (int g = 0; g < 4; g++) gl_lds16(bP[g] + k0, bL[g]);
        __syncthreads();
        short8 af[4], bfv[4];
        #pragma unroll
        for (int i = 0; i < 4; i++) af[i] = *(const short8*)&As[(i * 16 + fr) * 32 + quad * 8];
        #pragma unroll
        for (int j = 0; j < 4; j++) bfv[j] = *(const short8*)&Bs[(wn + j * 16 + fr) * 32 + quad * 8];
        #pragma unroll
        for (int i = 0; i < 4; i++)
            #pragma unroll
            for (int j = 0; j < 4; j++)
                acc[i][j] = __builtin_amdgcn_mfma_f32_16x16x32_bf16(af[i], bfv[j], acc[i][j], 0, 0, 0);
        __syncthreads();
    }
    // add bias
    #pragma unroll
    for (int j = 0; j < 4; j++) {
        float bv = bias[wn + j * 16 + fr];
        #pragma unroll
        for (int i = 0; i < 4; i++)
            #pragma unroll
            for (int r = 0; r < 4; r++) acc[i][j][r] += bv;
    }
    // row sums of squares (this wave's 64 cols), butterfly over fr bits
    #pragma unroll
    for (int i = 0; i < 4; i++) {
        #pragma unroll
        for (int r = 0; r < 4; r++) {
            float s = 0.f;
            #pragma unroll
            for (int j = 0; j < 4; j++) s += acc[i][j][r] * acc[i][j][r];
            #pragma unroll
            for (int o = 8; o > 0; o >>= 1) s += __shfl_xor(s, o);
            if (fr == 0) red[wave][i * 16 + quad * 4 + r] = s;
        }
    }
    __syncthreads();
    if (tid < 64) {
        float tot = red[0][tid] + red[1][tid] + red[2][tid] + red[3][tid];
        scl[tid] = rsqrtf(tot * (1.0f / CT) + 1e-5f);
    }
    __syncthreads();
    #pragma unroll
    for (int j = 0; j < 4; j++) {
        int n = wn + j * 16 + fr;
        float w = nw[n];
        #pragma unroll
        for (int i = 0; i < 4; i++) {
            int rl = i * 16 + quad * 4;
            #pragma unroll
            for (int r = 0; r < 4; r++) {
                float v = acc[i][j][r];
                Xo[(size_t)(m0 + rl + r) * CT + n] = f2b(v);
                XNo[(size_t)(m0 + rl + r) * CT + n] = f2b(v * scl[rl + r] * w);
            }
        }
    }
}

// ---- proj GEMM (K=256, N=256) with fused de-norm + transpose to fp32 out ----
// out[b, t, n] = (x @ projW + proj_b)[b*512+n, t] * stdev[b,n] + means[b,n]
__global__ __launch_bounds__(256) void proj_out_kernel(const bf16* __restrict__ A,
                                                       const bf16* __restrict__ Wt,
                                                       const float* __restrict__ bias,
                                                       const float* __restrict__ means,
                                                       const float* __restrict__ stdev,
                                                       float* __restrict__ out) {
    __shared__ __align__(16) short As[128 * 32];
    __shared__ __align__(16) short Bs[128 * 32];
    const int tid = threadIdx.x;
    const int lane = tid & 63;
    const int wave = tid >> 6;
    const int m0 = blockIdx.x * 128, n0 = blockIdx.y * 128;

    const int srow0 = wave * 32;
    const int lrow = lane >> 2;
    const int lcol = (lane & 3) * 8;
    const bf16* aP0 = A + (size_t)(m0 + srow0 + lrow) * 256 + lcol;
    const bf16* aP1 = A + (size_t)(m0 + srow0 + 16 + lrow) * 256 + lcol;
    const bf16* bP0 = Wt + (size_t)(n0 + srow0 + lrow) * 256 + lcol;
    const bf16* bP1 = Wt + (size_t)(n0 + srow0 + 16 + lrow) * 256 + lcol;
    short* aL0 = &As[srow0 * 32];
    short* aL1 = &As[(srow0 + 16) * 32];
    short* bL0 = &Bs[srow0 * 32];
    short* bL1 = &Bs[(srow0 + 16) * 32];

    const int wm = (wave & 1) * 64, wn = (wave >> 1) * 64;
    const int fr = lane & 15, quad = lane >> 4;

    floatx4 acc[4][4];
    #pragma unroll
    for (int i = 0; i < 4; i++)
        #pragma unroll
        for (int j = 0; j < 4; j++) acc[i][j] = (floatx4){0.f, 0.f, 0.f, 0.f};

    for (int k0 = 0; k0 < 256; k0 += 32) {
        gl_lds16(aP0 + k0, aL0);
        gl_lds16(aP1 + k0, aL1);
        gl_lds16(bP0 + k0, bL0);
        gl_lds16(bP1 + k0, bL1);
        __syncthreads();
        short8 af[4], bfv[4];
        #pragma unroll
        for (int i = 0; i < 4; i++) af[i] = *(const short8*)&As[(wm + i * 16 + fr) * 32 + quad * 8];
        #pragma unroll
        for (int j = 0; j < 4; j++) bfv[j] = *(const short8*)&Bs[(wn + j * 16 + fr) * 32 + quad * 8];
        #pragma unroll
        for (int i = 0; i < 4; i++)
            #pragma unroll
            for (int j = 0; j < 4; j++)
                acc[i][j] = __builtin_amdgcn_mfma_f32_16x16x32_bf16(af[i], bfv[j], acc[i][j], 0, 0, 0);
        __syncthreads();
    }
    #pragma unroll
    for (int j = 0; j < 4; j++) {
        int t = n0 + wn + j * 16 + fr;
        float bv = bias[t];
        #pragma unroll
        for (int i = 0; i < 4; i++) {
            int mb = m0 + wm + i * 16 + quad * 4;
            int b = mb >> 9;
            int nv = mb & 511;
            if (nv < CN) {
                floatx4 o;
                #pragma unroll
                for (int r = 0; r < 4; r++) {
                    int sn = b * CN + nv + r;
                    o[r] = (acc[i][j][r] + bv) * stdev[sn] + means[sn];
                }
                *(floatx4*)(out + ((size_t)(b * CT + t)) * CN + nv) = o;
            }
        }
    }
}

extern "C" void kernel_launch(void* const* d_in, const int* in_sizes, int n_in,
                              void* d_out, int out_size, void* d_ws, size_t ws_size,
                              hipStream_t stream) {
    const float* x_enc  = (const float*)d_in[0];
    const float* x_mark = (const float*)d_in[1];
    const float* norm_w = (const float*)d_in[4];
    const float* inp_W  = (const float*)d_in[5];
    const float* inp_b  = (const float*)d_in[6];
    const float* conv_W = (const float*)d_in[7];
    const float* conv_b = (const float*)d_in[8];
    const float* convlin_W = (const float*)d_in[9];
    const float* convlin_b = (const float*)d_in[10];
    const float* fc1_W = (const float*)d_in[11];
    const float* fc1_b = (const float*)d_in[12];
    const float* fc2_W = (const float*)d_in[13];
    const float* fc2_b = (const float*)d_in[14];
    const float* fc3_W = (const float*)d_in[15];
    const float* fc3_b = (const float*)d_in[16];
    const float* D_W   = (const float*)d_in[17];
    const float* D_b   = (const float*)d_in[18];
    const float* out_W = (const float*)d_in[19];
    const float* out_b = (const float*)d_in[20];
    const float* proj_W = (const float*)d_in[21];
    const float* proj_b = (const float*)d_in[22];

    // ---- workspace layout ----
    char* ws = (char*)d_ws;
    float* MEANS = (float*)(ws);
    float* STDEV = (float*)(ws + 65536);
    bf16* wt = (bf16*)(ws + 131072);
    bf16* wt_g1      = wt;                   // 3 x [1024][256]  (inp^T | D^T)
    bf16* wt_g3      = wt + 786432;          // 3 x [1024][512]  (fc1^T | fc2^T | fc3^T)
    bf16* wt_convlin = wt + 2359296;         // 3 x [512][512]
    bf16* wt_out     = wt + 3145728;         // 3 x [256][512]
    bf16* wt_proj    = wt + 3538944;         // [256][256]
    bf16* wt_conv    = wt + 3604480;         // 3 x [3][512][512]
    bf16* xpT = (bf16*)(ws + 12058624);      // [32][528][512]
    const size_t POOLB = 16777216;
    const size_t HALF = 16384 * 256;
    bf16* pool[3] = {
        (bf16*)(ws + 29360128),
        (bf16*)(ws + 29360128 + POOLB),
        (bf16*)(ws + 29360128 + 2 * POOLB),
    };
    bf16* E = (bf16*)(ws + 29360128 + 3 * POOLB);  // [16384][512]: Bmat|Cmat
    float* out = (float*)d_out;

    // ---- prepack: all 8 weight transposes in one kernel + convpack/pad ----
    P8 p;
    p.s[0] = inp_W;  p.d[0] = wt_g1;
    p.s[1] = D_W;    p.d[1] = wt_g1 + 131072;
    p.s[2] = fc1_W;  p.d[2] = wt_g3;
    p.s[3] = fc2_W;  p.d[3] = wt_g3 + 262144;
    p.s[4] = fc3_W;  p.d[4] = wt_g3 + 393216;
    p.s[5] = convlin_W; p.d[5] = wt_convlin;
    p.s[6] = out_W;  p.d[6] = wt_out;
    p.s[7] = proj_W; p.d[7] = wt_proj;
    prepack_all_kernel<<<3520, 256, 0, stream>>>(p);
    convpack_kernel<<<(CONVN + 32768 + 255) / 256, 256, 0, stream>>>(conv_W, wt_conv, xpT);

    // ---- fused stats + build + rmsnorm(iter0): xn -> pool[0].hi ----
    buildx_rms_kernel<<<MROWS, 256, 0, stream>>>(x_enc, x_mark, norm_w, MEANS, STDEV,
                                                 pool[0] + HALF);

    for (int i = 0; i < 3; i++) {
        bf16* A  = pool[i % 3];         // xn(hi) -> xc -> P/gate
        bf16* Bp = pool[(i + 1) % 3];   // xco -> x_next(lo)+xn_next(hi)
        bf16* Cp = pool[(i + 2) % 3];   // xres
        bf16* XN = A + HALF;

        // [xp|xres] = xn @ [inp|D] + b : xp -> xpT (transposed), xres -> Cp
        mgemm_kernel<1><<<dim3(128, 8), 256, 0, stream>>>(
            XN, wt_g1 + (size_t)i * 262144, inp_b + i * CT2, D_b + i * CT2, nullptr,
            xpT, Cp, 256, 1024);
        // xc = silu(conv(xp)) -> A
        conv_mfma_kernel<<<512, 256, 0, stream>>>(wt_conv + (size_t)i * 786432, xpT,
                                                  conv_b + i * CF, A);
        // xco = xc @ convlin + b -> Bp
        mgemm_kernel<0><<<dim3(128, 4), 256, 0, stream>>>(
            A, wt_convlin + (size_t)i * 262144, convlin_b + i * CT2, nullptr, nullptr,
            Bp, nullptr, 512, 512);
        // [P|Bmat|Cmat] = xco @ [fc1|fc2|fc3] + b : P -> A, Bmat|Cmat -> E
        mgemm_kernel<3><<<dim3(128, 8), 256, 0, stream>>>(
            Bp, wt_g3 + (size_t)i * 524288, fc1_b + i * CT2, fc2_b + i * CT, fc3_b + i * CT,
            A, E, 512, 1024);
        // gate in-place on A
        gate_kernel<<<MROWS, 256, 0, stream>>>(A, Bp, E, Cp);
        // x_next = gate @ out_W + b -> Bp.lo ; xn_next = rmsnorm(x_next) -> Bp.hi
        gemm_rms_kernel<<<256, 256, 0, stream>>>(
            A, wt_out + (size_t)i * 131072, out_b + i * CT,
            norm_w + ((i + 1) % 3) * CT, Bp, Bp + HALF);
    }

    // dec = x @ proj_W + b, de-normalized + transposed straight to fp32 out
    proj_out_kernel<<<dim3(128, 2), 256, 0, stream>>>(
        pool[0], wt_proj, proj_b, MEANS, STDEV, out);
}